// Round 1
// baseline (750.014 us; speedup 1.0000x reference)
//
#include <hip/hip_runtime.h>

// ---------------------------------------------------------------------------
// HypER pipeline on MI355X.
// Shapes: B=8192, N_ent=50000, D=400 (INPUT_D=D1=D2), OC=32, FW=9,
//         J = D-FW+1 = 392, R = OC*FW = 288, FCLEN = OC*J = 12544.
//
// Pipeline:
//   M    = W_E @ fc1_w.T                         (400x288)
//   head = UE[ht0] @ W_E                         (8192x400)
//   k    = UE[ht1] @ M + fc1_b                   (8192x288)
//   bn0 stats over head -> a0,b0 (x = a0*head+b0 applied in conv)
//   conv[b,o,j] = sum_w x[b,j+w]*k[b,o*9+w]  -> bf16 buffer + per-ch stats
//   bn1 -> alpha[o], beta[o]; fold: Bprep[d,c]=bf16(fc_w[d,c]*alpha),
//         bias2[d] = fc_b[d] + sum_c beta*fc_w[d,c]
//   pre  = conv_bf16 @ Bprep^T + bias2           (8192x400, bf16 MFMA)
//   bn2 per-column stats -> scale/shift -> relu  (in-place on d_out)
// ---------------------------------------------------------------------------

#define BB   8192
#define DD   400
#define RR   288
#define OCC  32
#define FWW  9
#define JJ   392
#define FCLEN 12544
#define EPSF 1e-5

typedef __attribute__((ext_vector_type(8))) short bf16x8;
typedef __attribute__((ext_vector_type(4))) float f32x4;

__device__ inline unsigned short f2bf(float f) {
    union { float f; unsigned u; } x; x.f = f;
    unsigned r = x.u + 0x7fffu + ((x.u >> 16) & 1u);
    return (unsigned short)(r >> 16);
}

__device__ inline float block_reduce_256(float v, float* red) {
    #pragma unroll
    for (int m = 1; m < 64; m <<= 1) v += __shfl_xor(v, m);
    int wv = threadIdx.x >> 6;
    if ((threadIdx.x & 63) == 0) red[wv] = v;
    __syncthreads();
    float r = 0.f;
    if (threadIdx.x == 0) r = red[0] + red[1] + red[2] + red[3];
    return r;
}

// ---------------- prep_M: M[i][r] = sum_d W_E[i][d]*fc1_w[r][d] ------------
__global__ __launch_bounds__(256) void prep_M(const float* __restrict__ WE,
                                              const float* __restrict__ f1w,
                                              float* __restrict__ Mout) {
    __shared__ float sA[16][17];
    __shared__ float sB[16][17];
    int tx = threadIdx.x, ty = threadIdx.y;
    int r0 = blockIdx.x * 16, i0 = blockIdx.y * 16;
    float acc = 0.f;
    for (int d0 = 0; d0 < DD; d0 += 16) {
        sA[ty][tx] = WE[(size_t)(i0 + ty) * DD + d0 + tx];
        sB[ty][tx] = f1w[(size_t)(r0 + ty) * DD + d0 + tx];
        __syncthreads();
        #pragma unroll
        for (int dd = 0; dd < 16; ++dd) acc = fmaf(sA[ty][dd], sB[tx][dd], acc);
        __syncthreads();
    }
    Mout[(size_t)(i0 + ty) * RR + r0 + tx] = acc;
}

// ------------- stage-1 gathered GEMM: C = bf16(UE[idx]) @ bf16(Bm) --------
template <int BN>
__global__ __launch_bounds__(256) void gemm_s1(const float* __restrict__ A,
                                               const int* __restrict__ idx,
                                               const float* __restrict__ Bm,
                                               const float* __restrict__ bias,
                                               float* __restrict__ C, int N) {
    constexpr int BNF = BN / 16;
    __shared__ unsigned short Al[128][72];
    __shared__ unsigned short Bl[BN][72];
    __shared__ int ridx[128];
    int tid = threadIdx.x;
    int bm = blockIdx.x, bn = blockIdx.y;
    if (tid < 128) ridx[tid] = idx[bm * 128 + tid];
    int lane = tid & 63, wv = tid >> 6;
    int m16 = lane & 15, kb = lane >> 4;
    f32x4 acc[2][BNF];
    #pragma unroll
    for (int mi = 0; mi < 2; ++mi)
        #pragma unroll
        for (int nb = 0; nb < BNF; ++nb) acc[mi][nb] = (f32x4){0.f, 0.f, 0.f, 0.f};
    __syncthreads();
    for (int k0 = 0; k0 < DD; k0 += 64) {
        // stage A: 128 rows x 64 cols, f32 -> bf16
        #pragma unroll
        for (int r = 0; r < 8; ++r) {
            int c = tid + 256 * r;
            int row = c >> 4, kq = c & 15;
            int gk = k0 + kq * 4;
            float4 v = {0.f, 0.f, 0.f, 0.f};
            if (gk < DD) v = *(const float4*)(A + (size_t)ridx[row] * DD + gk);
            ushort4 p;
            p.x = f2bf(v.x); p.y = f2bf(v.y); p.z = f2bf(v.z); p.w = f2bf(v.w);
            *(ushort4*)&Al[row][kq * 4] = p;
        }
        // stage B transposed: Bl[n][k] = Bm[k][n]
        constexpr int BC = 64 * (BN / 4);
        #pragma unroll
        for (int r = 0; r < (BC + 255) / 256; ++r) {
            int c = tid + 256 * r;
            if (c < BC) {
                int kk = c / (BN / 4), nq = c % (BN / 4);
                int gk = k0 + kk;
                float4 v = {0.f, 0.f, 0.f, 0.f};
                if (gk < DD) v = *(const float4*)(Bm + (size_t)gk * N + bn * BN + nq * 4);
                Bl[nq * 4 + 0][kk] = f2bf(v.x);
                Bl[nq * 4 + 1][kk] = f2bf(v.y);
                Bl[nq * 4 + 2][kk] = f2bf(v.z);
                Bl[nq * 4 + 3][kk] = f2bf(v.w);
            }
        }
        __syncthreads();
        #pragma unroll
        for (int ks = 0; ks < 2; ++ks) {
            bf16x8 a[2], b[BNF];
            #pragma unroll
            for (int mi = 0; mi < 2; ++mi)
                a[mi] = *(const bf16x8*)&Al[wv * 32 + mi * 16 + m16][ks * 32 + kb * 8];
            #pragma unroll
            for (int nb = 0; nb < BNF; ++nb)
                b[nb] = *(const bf16x8*)&Bl[nb * 16 + m16][ks * 32 + kb * 8];
            #pragma unroll
            for (int mi = 0; mi < 2; ++mi)
                #pragma unroll
                for (int nb = 0; nb < BNF; ++nb)
                    acc[mi][nb] = __builtin_amdgcn_mfma_f32_16x16x32_bf16(a[mi], b[nb], acc[mi][nb], 0, 0, 0);
        }
        __syncthreads();
    }
    #pragma unroll
    for (int mi = 0; mi < 2; ++mi)
        #pragma unroll
        for (int nb = 0; nb < BNF; ++nb)
            #pragma unroll
            for (int rr = 0; rr < 4; ++rr) {
                int gr = bm * 128 + wv * 32 + mi * 16 + kb * 4 + rr;
                int gc = bn * BN + nb * 16 + m16;
                float v = acc[mi][nb][rr];
                if (bias) v += bias[gc];
                C[(size_t)gr * N + gc] = v;
            }
}

// ---------------- bn0 stats over head (scalar mean/var) --------------------
__global__ __launch_bounds__(256) void bn0_part(const float* __restrict__ head,
                                                float* __restrict__ part) {
    __shared__ float red[8];
    const size_t total4 = (size_t)BB * DD / 4;
    float s1 = 0.f, s2 = 0.f;
    for (size_t i = (size_t)blockIdx.x * 256 + threadIdx.x; i < total4; i += 256 * 256) {
        float4 v = ((const float4*)head)[i];
        s1 += v.x + v.y + v.z + v.w;
        s2 += v.x * v.x + v.y * v.y + v.z * v.z + v.w * v.w;
    }
    float t1 = block_reduce_256(s1, red);
    float t2 = block_reduce_256(s2, red + 4);
    if (threadIdx.x == 0) { part[blockIdx.x * 2] = t1; part[blockIdx.x * 2 + 1] = t2; }
}

__global__ __launch_bounds__(256) void bn0_fin(const float* __restrict__ part,
                                               const float* __restrict__ g,
                                               const float* __restrict__ b,
                                               float* __restrict__ ab0) {
    __shared__ float red[8];
    float s1 = part[threadIdx.x * 2], s2 = part[threadIdx.x * 2 + 1];
    float t1 = block_reduce_256(s1, red);
    float t2 = block_reduce_256(s2, red + 4);
    if (threadIdx.x == 0) {
        double n = (double)BB * DD;
        double mean = (double)t1 / n;
        double var = (double)t2 / n - mean * mean;
        float a0 = (float)((double)g[0] / sqrt(var + EPSF));
        float b0 = (float)((double)b[0] - mean * a0);
        ab0[0] = a0; ab0[1] = b0;
    }
}

// --------------- per-sample conv + bn1 partial stats -----------------------
__global__ __launch_bounds__(256) void conv_k(const float* __restrict__ head,
                                              const float* __restrict__ kbuf,
                                              const float* __restrict__ ab0,
                                              unsigned short* __restrict__ convb,
                                              float* __restrict__ chpart) {
    __shared__ float xs[408];
    __shared__ float ks[RR];
    __shared__ float wred[OCC][4][2];
    int b = blockIdx.x, tid = threadIdx.x;
    float a0 = ab0[0], b0 = ab0[1];
    for (int i = tid; i < DD; i += 256) xs[i] = fmaf(head[(size_t)b * DD + i], a0, b0);
    for (int i = tid; i < RR; i += 256) ks[i] = kbuf[(size_t)b * RR + i];
    __syncthreads();
    int lane = tid & 63, wv = tid >> 6;
    unsigned short* orow = convb + (size_t)b * FCLEN;
    for (int o = 0; o < OCC; ++o) {
        float kk[FWW];
        #pragma unroll
        for (int w2 = 0; w2 < FWW; ++w2) kk[w2] = ks[o * FWW + w2];
        float s1 = 0.f, s2 = 0.f;
        for (int j = tid; j < JJ; j += 256) {
            float acc = 0.f;
            #pragma unroll
            for (int w2 = 0; w2 < FWW; ++w2) acc = fmaf(xs[j + w2], kk[w2], acc);
            orow[o * JJ + j] = f2bf(acc);
            s1 += acc; s2 = fmaf(acc, acc, s2);
        }
        #pragma unroll
        for (int m = 1; m < 64; m <<= 1) { s1 += __shfl_xor(s1, m); s2 += __shfl_xor(s2, m); }
        if (lane == 0) { wred[o][wv][0] = s1; wred[o][wv][1] = s2; }
    }
    __syncthreads();
    if (tid < 64) {
        int o = tid >> 1, v = tid & 1;
        float s = wred[o][0][v] + wred[o][1][v] + wred[o][2][v] + wred[o][3][v];
        chpart[((size_t)b * OCC + o) * 2 + v] = s;
    }
}

__global__ __launch_bounds__(256) void bn1_fin(const float* __restrict__ chpart,
                                               const float* __restrict__ g1,
                                               const float* __restrict__ b1,
                                               float* __restrict__ alphabeta) {
    __shared__ float red[8];
    int o = blockIdx.x, tid = threadIdx.x;
    float s1 = 0.f, s2 = 0.f;
    for (int b = tid; b < BB; b += 256) {
        s1 += chpart[((size_t)b * OCC + o) * 2 + 0];
        s2 += chpart[((size_t)b * OCC + o) * 2 + 1];
    }
    float t1 = block_reduce_256(s1, red);
    float t2 = block_reduce_256(s2, red + 4);
    if (tid == 0) {
        double n = (double)BB * JJ;
        double mean = (double)t1 / n;
        double var = (double)t2 / n - mean * mean;
        float al = (float)((double)g1[o] / sqrt(var + EPSF));
        float be = (float)((double)b1[o] - mean * al);
        alphabeta[o] = al; alphabeta[OCC + o] = be;
    }
}

// ------- fold bn1 into fc_w: Bprep = bf16(fc_w*alpha); bias2 ---------------
__global__ __launch_bounds__(256) void prep_fcw(const float* __restrict__ fc_w,
                                                const float* __restrict__ fc_b,
                                                const float* __restrict__ alphabeta,
                                                unsigned short* __restrict__ Bp,
                                                float* __restrict__ bias2) {
    __shared__ float al[OCC], be[OCC];
    __shared__ float red[8];
    int d = blockIdx.x, tid = threadIdx.x;
    if (tid < OCC) { al[tid] = alphabeta[tid]; be[tid] = alphabeta[OCC + tid]; }
    __syncthreads();
    const float* row = fc_w + (size_t)d * FCLEN;
    unsigned short* orow = Bp + (size_t)d * FCLEN;
    float bacc = 0.f;
    for (int o = 0; o < OCC; ++o) {
        float a = al[o], bb = be[o];
        for (int j = tid; j < JJ; j += 256) {
            float wv = row[o * JJ + j];
            orow[o * JJ + j] = f2bf(wv * a);
            bacc = fmaf(wv, bb, bacc);
        }
    }
    float t = block_reduce_256(bacc, red);
    if (tid == 0) bias2[d] = fc_b[d] + t;
}

// ---------------- big FC GEMM: pre = conv_bf16 @ Bprep^T + bias2 -----------
__global__ __launch_bounds__(256) void fc_gemm(const unsigned short* __restrict__ A,
                                               const unsigned short* __restrict__ Bp,
                                               const float* __restrict__ bias2,
                                               float* __restrict__ C) {
    __shared__ unsigned short Al[128][72];
    __shared__ unsigned short Bl[80][72];
    int tid = threadIdx.x;
    int bm = blockIdx.x, bn = blockIdx.y;
    int lane = tid & 63, wv = tid >> 6;
    int m16 = lane & 15, kb = lane >> 4;
    f32x4 acc[2][5];
    #pragma unroll
    for (int mi = 0; mi < 2; ++mi)
        #pragma unroll
        for (int nb = 0; nb < 5; ++nb) acc[mi][nb] = (f32x4){0.f, 0.f, 0.f, 0.f};
    const size_t K = FCLEN;
    for (int kt = 0; kt < FCLEN / 64; ++kt) {
        int k0 = kt * 64;
        #pragma unroll
        for (int r = 0; r < 4; ++r) {
            int c = tid + 256 * r;   // 1024 chunks of 16B
            int row = c >> 3, kc = c & 7;
            uint4 v = *(const uint4*)(A + (size_t)(bm * 128 + row) * K + k0 + kc * 8);
            *(uint4*)&Al[row][kc * 8] = v;
        }
        #pragma unroll
        for (int r = 0; r < 3; ++r) {
            int c = tid + 256 * r;   // 640 chunks
            if (c < 640) {
                int row = c >> 3, kc = c & 7;
                uint4 v = *(const uint4*)(Bp + (size_t)(bn * 80 + row) * K + k0 + kc * 8);
                *(uint4*)&Bl[row][kc * 8] = v;
            }
        }
        __syncthreads();
        #pragma unroll
        for (int ks = 0; ks < 2; ++ks) {
            bf16x8 a[2], b[5];
            #pragma unroll
            for (int mi = 0; mi < 2; ++mi)
                a[mi] = *(const bf16x8*)&Al[wv * 32 + mi * 16 + m16][ks * 32 + kb * 8];
            #pragma unroll
            for (int nb = 0; nb < 5; ++nb)
                b[nb] = *(const bf16x8*)&Bl[nb * 16 + m16][ks * 32 + kb * 8];
            #pragma unroll
            for (int mi = 0; mi < 2; ++mi)
                #pragma unroll
                for (int nb = 0; nb < 5; ++nb)
                    acc[mi][nb] = __builtin_amdgcn_mfma_f32_16x16x32_bf16(a[mi], b[nb], acc[mi][nb], 0, 0, 0);
        }
        __syncthreads();
    }
    #pragma unroll
    for (int mi = 0; mi < 2; ++mi)
        #pragma unroll
        for (int nb = 0; nb < 5; ++nb)
            #pragma unroll
            for (int rr = 0; rr < 4; ++rr) {
                int gr = bm * 128 + wv * 32 + mi * 16 + kb * 4 + rr;
                int gc = bn * 80 + nb * 16 + m16;
                C[(size_t)gr * DD + gc] = acc[mi][nb][rr] + bias2[gc];
            }
}

// ---------------- bn2: per-column stats + finalize + relu ------------------
__global__ __launch_bounds__(256) void bn2_part(const float* __restrict__ pre,
                                                float* __restrict__ part) {
    int blk = blockIdx.x, tid = threadIdx.x;
    int r0 = blk * 64;
    float s1a = 0.f, s2a = 0.f, s1b = 0.f, s2b = 0.f;
    for (int r = 0; r < 64; ++r) {
        const float* rp = pre + (size_t)(r0 + r) * DD;
        float v = rp[tid];
        s1a += v; s2a = fmaf(v, v, s2a);
        if (tid < DD - 256) {
            float u = rp[256 + tid];
            s1b += u; s2b = fmaf(u, u, s2b);
        }
    }
    float* p = part + (size_t)blk * (DD * 2);
    p[tid * 2] = s1a; p[tid * 2 + 1] = s2a;
    if (tid < DD - 256) { p[(256 + tid) * 2] = s1b; p[(256 + tid) * 2 + 1] = s2b; }
}

__global__ __launch_bounds__(128) void bn2_fin(const float* __restrict__ part,
                                               const float* __restrict__ g2,
                                               const float* __restrict__ b2,
                                               float* __restrict__ sc,
                                               float* __restrict__ sh) {
    __shared__ float red[4];
    int col = blockIdx.x, tid = threadIdx.x;
    float s1 = part[(size_t)tid * (DD * 2) + col * 2];
    float s2 = part[(size_t)tid * (DD * 2) + col * 2 + 1];
    #pragma unroll
    for (int m = 1; m < 64; m <<= 1) { s1 += __shfl_xor(s1, m); s2 += __shfl_xor(s2, m); }
    int wv = tid >> 6;
    if ((tid & 63) == 0) { red[wv] = s1; red[2 + wv] = s2; }
    __syncthreads();
    if (tid == 0) {
        double t1 = (double)red[0] + red[1];
        double t2 = (double)red[2] + red[3];
        double mean = t1 / (double)BB;
        double var = t2 / (double)BB - mean * mean;
        float s = (float)((double)g2[col] / sqrt(var + EPSF));
        sc[col] = s;
        sh[col] = (float)((double)b2[col] - mean * s);
    }
}

__global__ __launch_bounds__(256) void final_k(float* __restrict__ out,
                                               const float* __restrict__ sc,
                                               const float* __restrict__ sh) {
    __shared__ float lsc[DD], lsh[DD];
    int tid = threadIdx.x;
    for (int c = tid; c < DD; c += 256) { lsc[c] = sc[c]; lsh[c] = sh[c]; }
    __syncthreads();
    size_t base = (size_t)blockIdx.x * 4 * DD;
    for (int r = 0; r < 4; ++r)
        for (int c = tid; c < DD; c += 256) {
            size_t i = base + (size_t)r * DD + c;
            float v = fmaf(out[i], lsc[c], lsh[c]);
            out[i] = v > 0.f ? v : 0.f;
        }
}

// ---------------------------------------------------------------------------
extern "C" void kernel_launch(void* const* d_in, const int* in_sizes, int n_in,
                              void* d_out, int out_size, void* d_ws, size_t ws_size,
                              hipStream_t stream) {
    const int* ht      = (const int*)d_in[0];
    const float* UE    = (const float*)d_in[1];
    const float* W_E   = (const float*)d_in[2];
    const float* fc1_w = (const float*)d_in[3];
    const float* fc1_b = (const float*)d_in[4];
    const float* fc_w  = (const float*)d_in[5];
    const float* fc_b  = (const float*)d_in[6];
    const float* bn0_g = (const float*)d_in[7];
    const float* bn0_b = (const float*)d_in[8];
    const float* bn1_g = (const float*)d_in[9];
    const float* bn1_b = (const float*)d_in[10];
    const float* bn2_g = (const float*)d_in[11];
    const float* bn2_b = (const float*)d_in[12];
    float* out = (float*)d_out;

    char* w = (char*)d_ws;
    unsigned short* convb = (unsigned short*)w; w += (size_t)BB * FCLEN * 2;
    float* head = (float*)w;  w += (size_t)BB * DD * 4;
    float* kbuf = (float*)w;  w += (size_t)BB * RR * 4;
    float* Mbuf = (float*)w;  w += (size_t)DD * RR * 4;
    unsigned short* Bprep = (unsigned short*)w; w += (size_t)DD * FCLEN * 2;
    float* bn0p = (float*)w;  w += 256 * 2 * 4;
    float* ab0 = (float*)w;   w += 64;
    float* chpart = (float*)w; w += (size_t)BB * OCC * 2 * 4;
    float* alphabeta = (float*)w; w += 64 * 4;
    float* bias2 = (float*)w; w += DD * 4;
    float* bn2p = (float*)w;  w += (size_t)128 * DD * 2 * 4;
    float* bn2sc = (float*)w; w += DD * 4;
    float* bn2sh = (float*)w; w += DD * 4;
    (void)ws_size; (void)in_sizes; (void)n_in; (void)out_size;

    prep_M<<<dim3(RR / 16, DD / 16), dim3(16, 16), 0, stream>>>(W_E, fc1_w, Mbuf);
    gemm_s1<80><<<dim3(BB / 128, DD / 80), 256, 0, stream>>>(UE, ht, W_E, nullptr, head, DD);
    gemm_s1<96><<<dim3(BB / 128, RR / 96), 256, 0, stream>>>(UE, ht + BB, Mbuf, fc1_b, kbuf, RR);
    bn0_part<<<256, 256, 0, stream>>>(head, bn0p);
    bn0_fin<<<1, 256, 0, stream>>>(bn0p, bn0_g, bn0_b, ab0);
    conv_k<<<BB, 256, 0, stream>>>(head, kbuf, ab0, convb, chpart);
    bn1_fin<<<OCC, 256, 0, stream>>>(chpart, bn1_g, bn1_b, alphabeta);
    prep_fcw<<<DD, 256, 0, stream>>>(fc_w, fc_b, alphabeta, Bprep, bias2);
    fc_gemm<<<dim3(BB / 128, DD / 80), 256, 0, stream>>>(convb, Bprep, bias2, out);
    bn2_part<<<128, 256, 0, stream>>>(out, bn2p);
    bn2_fin<<<DD, 128, 0, stream>>>(bn2p, bn2_g, bn2_b, bn2sc, bn2sh);
    final_k<<<2048, 256, 0, stream>>>(out, bn2sc, bn2sh);
}

// Round 2
// 402.133 us; speedup vs baseline: 1.8651x; 1.8651x over previous
//
#include <hip/hip_runtime.h>

// ---------------------------------------------------------------------------
// HypER pipeline on MI355X. B=8192, D=400, OC=32, FW=9, J=392, R=288,
// FCLEN=12544.
//   M    = W_E @ fc1_w.T            (400x288)      prep_M
//   head = bf16(UE[ht0]) @ bf16(W_E)               gemm_s1<80>
//   k    = bf16(UE[ht1]) @ bf16(M) + fc1_b         gemm_s1<96>
//   bn0 -> a0,b0 scalars                           bn0_part/bn0_fin
//   conv[b,o,j] -> bf16 convb + per-ch stats       conv_k (wave-per-channel)
//   bn1 -> alpha,beta; fold into fc_w              bn1_fin, prep_fcw
//   pre  = convb @ Bprep^T  (split-K=4, MFMA,      fc_gemm_sk
//          global_load_lds + XOR swizzle)
//   reduce partials + bias + bn2 partial stats     reduce_bn2
//   bn2 finalize + relu                            bn2_fin, final_k
// ---------------------------------------------------------------------------

#define BB   8192
#define DD   400
#define RR   288
#define OCC  32
#define FWW  9
#define JJ   392
#define FCLEN 12544
#define KSPL 4
#define KS   (FCLEN / KSPL)   /* 3136 */
#define KSTEPS (KS / 64)      /* 49 */
#define EPSF 1e-5

typedef __attribute__((ext_vector_type(8))) short bf16x8;
typedef __attribute__((ext_vector_type(4))) float f32x4;

__device__ inline unsigned short f2bf(float f) {
    union { float f; unsigned u; } x; x.f = f;
    unsigned r = x.u + 0x7fffu + ((x.u >> 16) & 1u);
    return (unsigned short)(r >> 16);
}

__device__ inline void gload16(const void* g, void* l) {
    __builtin_amdgcn_global_load_lds((const __attribute__((address_space(1))) unsigned int*)g,
                                     (__attribute__((address_space(3))) unsigned int*)l, 16, 0, 0);
}

__device__ inline float block_reduce_256(float v, float* red) {
    #pragma unroll
    for (int m = 1; m < 64; m <<= 1) v += __shfl_xor(v, m);
    int wv = threadIdx.x >> 6;
    if ((threadIdx.x & 63) == 0) red[wv] = v;
    __syncthreads();
    float r = 0.f;
    if (threadIdx.x == 0) r = red[0] + red[1] + red[2] + red[3];
    return r;
}

// ---------------- prep_M: M[i][r] = sum_d W_E[i][d]*fc1_w[r][d] ------------
__global__ __launch_bounds__(256) void prep_M(const float* __restrict__ WE,
                                              const float* __restrict__ f1w,
                                              float* __restrict__ Mout) {
    __shared__ float sA[16][17];
    __shared__ float sB[16][17];
    int tx = threadIdx.x, ty = threadIdx.y;
    int r0 = blockIdx.x * 16, i0 = blockIdx.y * 16;
    float acc = 0.f;
    for (int d0 = 0; d0 < DD; d0 += 16) {
        sA[ty][tx] = WE[(size_t)(i0 + ty) * DD + d0 + tx];
        sB[ty][tx] = f1w[(size_t)(r0 + ty) * DD + d0 + tx];
        __syncthreads();
        #pragma unroll
        for (int dd = 0; dd < 16; ++dd) acc = fmaf(sA[ty][dd], sB[tx][dd], acc);
        __syncthreads();
    }
    Mout[(size_t)(i0 + ty) * RR + r0 + tx] = acc;
}

// ------------- stage-1 gathered GEMM: BM=64, C = bf16(UE[idx]) @ bf16(Bm) --
template <int BN>
__global__ __launch_bounds__(256) void gemm_s1(const float* __restrict__ A,
                                               const int* __restrict__ idx,
                                               const float* __restrict__ Bm,
                                               const float* __restrict__ bias,
                                               float* __restrict__ C, int N) {
    constexpr int BNF = BN / 16;
    __shared__ unsigned short Al[64][72];
    __shared__ unsigned short Bl[BN][72];
    __shared__ int ridx[64];
    int tid = threadIdx.x;
    int bm = blockIdx.x, bn = blockIdx.y;
    if (tid < 64) ridx[tid] = idx[bm * 64 + tid];
    int lane = tid & 63, wv = tid >> 6;
    int m16 = lane & 15, kb = lane >> 4;
    f32x4 acc[BNF];
    #pragma unroll
    for (int nb = 0; nb < BNF; ++nb) acc[nb] = (f32x4){0.f, 0.f, 0.f, 0.f};
    __syncthreads();
    for (int k0 = 0; k0 < DD; k0 += 64) {
        // stage A: 64 rows x 64 cols, f32 -> bf16 (64*16=1024 float4 chunks)
        #pragma unroll
        for (int r = 0; r < 4; ++r) {
            int c = tid + 256 * r;
            int row = c >> 4, kq = c & 15;
            int gk = k0 + kq * 4;
            float4 v = {0.f, 0.f, 0.f, 0.f};
            if (gk < DD) v = *(const float4*)(A + (size_t)ridx[row] * DD + gk);
            ushort4 p;
            p.x = f2bf(v.x); p.y = f2bf(v.y); p.z = f2bf(v.z); p.w = f2bf(v.w);
            *(ushort4*)&Al[row][kq * 4] = p;
        }
        // stage B transposed: Bl[n][k] = Bm[k][n]
        constexpr int BC = 64 * (BN / 4);
        #pragma unroll
        for (int r = 0; r < (BC + 255) / 256; ++r) {
            int c = tid + 256 * r;
            if (c < BC) {
                int kk = c / (BN / 4), nq = c % (BN / 4);
                int gk = k0 + kk;
                float4 v = {0.f, 0.f, 0.f, 0.f};
                if (gk < DD) v = *(const float4*)(Bm + (size_t)gk * N + bn * BN + nq * 4);
                Bl[nq * 4 + 0][kk] = f2bf(v.x);
                Bl[nq * 4 + 1][kk] = f2bf(v.y);
                Bl[nq * 4 + 2][kk] = f2bf(v.z);
                Bl[nq * 4 + 3][kk] = f2bf(v.w);
            }
        }
        __syncthreads();
        #pragma unroll
        for (int ks = 0; ks < 2; ++ks) {
            bf16x8 a = *(const bf16x8*)&Al[wv * 16 + m16][ks * 32 + kb * 8];
            #pragma unroll
            for (int nb = 0; nb < BNF; ++nb) {
                bf16x8 b = *(const bf16x8*)&Bl[nb * 16 + m16][ks * 32 + kb * 8];
                acc[nb] = __builtin_amdgcn_mfma_f32_16x16x32_bf16(a, b, acc[nb], 0, 0, 0);
            }
        }
        __syncthreads();
    }
    #pragma unroll
    for (int nb = 0; nb < BNF; ++nb)
        #pragma unroll
        for (int rr = 0; rr < 4; ++rr) {
            int gr = bm * 64 + wv * 16 + kb * 4 + rr;
            int gc = bn * BN + nb * 16 + m16;
            float v = acc[nb][rr];
            if (bias) v += bias[gc];
            C[(size_t)gr * N + gc] = v;
        }
}

// ---------------- bn0 stats over head (scalar mean/var) --------------------
__global__ __launch_bounds__(256) void bn0_part(const float* __restrict__ head,
                                                float* __restrict__ part) {
    __shared__ float red[8];
    const size_t total4 = (size_t)BB * DD / 4;
    float s1 = 0.f, s2 = 0.f;
    for (size_t i = (size_t)blockIdx.x * 256 + threadIdx.x; i < total4; i += 256 * 256) {
        float4 v = ((const float4*)head)[i];
        s1 += v.x + v.y + v.z + v.w;
        s2 += v.x * v.x + v.y * v.y + v.z * v.z + v.w * v.w;
    }
    float t1 = block_reduce_256(s1, red);
    float t2 = block_reduce_256(s2, red + 4);
    if (threadIdx.x == 0) { part[blockIdx.x * 2] = t1; part[blockIdx.x * 2 + 1] = t2; }
}

__global__ __launch_bounds__(256) void bn0_fin(const float* __restrict__ part,
                                               const float* __restrict__ g,
                                               const float* __restrict__ b,
                                               float* __restrict__ ab0) {
    __shared__ float red[8];
    float s1 = part[threadIdx.x * 2], s2 = part[threadIdx.x * 2 + 1];
    float t1 = block_reduce_256(s1, red);
    float t2 = block_reduce_256(s2, red + 4);
    if (threadIdx.x == 0) {
        double n = (double)BB * DD;
        double mean = (double)t1 / n;
        double var = (double)t2 / n - mean * mean;
        float a0 = (float)((double)g[0] / sqrt(var + EPSF));
        float b0 = (float)((double)b[0] - mean * a0);
        ab0[0] = a0; ab0[1] = b0;
    }
}

// --------------- per-sample conv: wave owns 8 channels ---------------------
__global__ __launch_bounds__(256) void conv_k(const float* __restrict__ head,
                                              const float* __restrict__ kbuf,
                                              const float* __restrict__ ab0,
                                              unsigned short* __restrict__ convb,
                                              float* __restrict__ chpartT) {
    __shared__ float xs[DD + 8];
    __shared__ float ks[RR];
    int b = blockIdx.x, tid = threadIdx.x;
    float a0 = ab0[0], b0 = ab0[1];
    for (int i = tid; i < DD; i += 256) xs[i] = fmaf(head[(size_t)b * DD + i], a0, b0);
    for (int i = tid; i < RR; i += 256) ks[i] = kbuf[(size_t)b * RR + i];
    __syncthreads();
    int lane = tid & 63, wv = tid >> 6;
    unsigned short* orow = convb + (size_t)b * FCLEN;
    #pragma unroll
    for (int oi = 0; oi < 8; ++oi) {
        int o = wv * 8 + oi;
        float kk[FWW];
        #pragma unroll
        for (int w2 = 0; w2 < FWW; ++w2) kk[w2] = ks[o * FWW + w2];
        float s1 = 0.f, s2 = 0.f;
        #pragma unroll
        for (int jt = 0; jt < 7; ++jt) {
            int j = jt * 64 + lane;
            if (j < JJ) {
                float acc = 0.f;
                #pragma unroll
                for (int w2 = 0; w2 < FWW; ++w2) acc = fmaf(xs[j + w2], kk[w2], acc);
                orow[o * JJ + j] = f2bf(acc);
                s1 += acc; s2 = fmaf(acc, acc, s2);
            }
        }
        #pragma unroll
        for (int m = 1; m < 64; m <<= 1) { s1 += __shfl_xor(s1, m); s2 += __shfl_xor(s2, m); }
        if (lane == 0) {
            chpartT[(size_t)o * BB + b] = s1;
            chpartT[(size_t)(OCC + o) * BB + b] = s2;
        }
    }
}

__global__ __launch_bounds__(256) void bn1_fin(const float* __restrict__ chpartT,
                                               const float* __restrict__ g1,
                                               const float* __restrict__ b1,
                                               float* __restrict__ alphabeta) {
    __shared__ float red[8];
    int o = blockIdx.x, tid = threadIdx.x;
    float s1 = 0.f, s2 = 0.f;
    for (int t = tid; t < BB; t += 256) {
        s1 += chpartT[(size_t)o * BB + t];
        s2 += chpartT[(size_t)(OCC + o) * BB + t];
    }
    float t1 = block_reduce_256(s1, red);
    float t2 = block_reduce_256(s2, red + 4);
    if (tid == 0) {
        double n = (double)BB * JJ;
        double mean = (double)t1 / n;
        double var = (double)t2 / n - mean * mean;
        float al = (float)((double)g1[o] / sqrt(var + EPSF));
        float be = (float)((double)b1[o] - mean * al);
        alphabeta[o] = al; alphabeta[OCC + o] = be;
    }
}

// ------- fold bn1 into fc_w: Bprep = bf16(fc_w*alpha); bias2 ---------------
__global__ __launch_bounds__(256) void prep_fcw(const float* __restrict__ fc_w,
                                                const float* __restrict__ fc_b,
                                                const float* __restrict__ alphabeta,
                                                unsigned short* __restrict__ Bp,
                                                float* __restrict__ bias2) {
    __shared__ float al[OCC], be[OCC];
    __shared__ float red[8];
    int d = blockIdx.x, tid = threadIdx.x;
    if (tid < OCC) { al[tid] = alphabeta[tid]; be[tid] = alphabeta[OCC + tid]; }
    __syncthreads();
    const float* row = fc_w + (size_t)d * FCLEN;
    unsigned short* orow = Bp + (size_t)d * FCLEN;
    float bacc = 0.f;
    for (int o = 0; o < OCC; ++o) {
        float a = al[o], bb = be[o];
        for (int j = tid; j < JJ; j += 256) {
            float wv = row[o * JJ + j];
            orow[o * JJ + j] = f2bf(wv * a);
            bacc = fmaf(wv, bb, bacc);
        }
    }
    float t = block_reduce_256(bacc, red);
    if (tid == 0) bias2[d] = fc_b[d] + t;
}

// -------- big FC GEMM, split-K=4, global_load_lds + XOR swizzle ------------
// LDS linear; source pre-swizzled per-lane; ds_read applies same XOR.
__global__ __launch_bounds__(256, 4) void fc_gemm_sk(const unsigned short* __restrict__ A,
                                                     const unsigned short* __restrict__ Bp,
                                                     float* __restrict__ P) {
    __shared__ unsigned short Al[128 * 64];   // 16 KiB, 16 chunks of 1 KiB
    __shared__ unsigned short Bl[80 * 64];    // 10 KiB, 10 chunks
    int tid = threadIdx.x;
    int bm = blockIdx.x, bn = blockIdx.y, bz = blockIdx.z;
    int lane = tid & 63, wv = tid >> 6;
    int m16 = lane & 15, kb = lane >> 4;
    int srow = lane >> 3, scol = lane & 7;    // staging: 8 rows x 8 chunks per 1KiB
    int sw = m16 & 7;                          // read-side XOR (row&7)
    f32x4 acc[2][5];
    #pragma unroll
    for (int mi = 0; mi < 2; ++mi)
        #pragma unroll
        for (int nb = 0; nb < 5; ++nb) acc[mi][nb] = (f32x4){0.f, 0.f, 0.f, 0.f};
    // per-lane global bases (chunk column pre-swizzled by srow)
    const unsigned short* Ab = A + (size_t)(bm * 128 + srow) * FCLEN + (size_t)bz * KS + ((scol ^ srow) << 3);
    const unsigned short* Bb = Bp + (size_t)(bn * 80 + srow) * FCLEN + (size_t)bz * KS + ((scol ^ srow) << 3);
    for (int kt = 0; kt < KSTEPS; ++kt) {
        const size_t koff = (size_t)kt * 64;
        #pragma unroll
        for (int i = 0; i < 7; ++i) {
            int c = wv + i * 4;               // wave-uniform chunk id
            if (c < 16) {
                gload16(Ab + (size_t)c * 8 * FCLEN + koff, Al + c * 512);
            } else if (c < 26) {
                int cb = c - 16;
                gload16(Bb + (size_t)cb * 8 * FCLEN + koff, Bl + cb * 512);
            }
        }
        __syncthreads();
        int rA0 = (wv * 32 + m16) * 64;
        int rA1 = rA0 + 16 * 64;
        #pragma unroll
        for (int ks2 = 0; ks2 < 2; ++ks2) {
            int ch = (((ks2 * 4 + kb) ^ sw) << 3);
            bf16x8 a0 = *(const bf16x8*)(Al + rA0 + ch);
            bf16x8 a1 = *(const bf16x8*)(Al + rA1 + ch);
            #pragma unroll
            for (int nb = 0; nb < 5; ++nb) {
                bf16x8 b = *(const bf16x8*)(Bl + (nb * 16 + m16) * 64 + ch);
                acc[0][nb] = __builtin_amdgcn_mfma_f32_16x16x32_bf16(a0, b, acc[0][nb], 0, 0, 0);
                acc[1][nb] = __builtin_amdgcn_mfma_f32_16x16x32_bf16(a1, b, acc[1][nb], 0, 0, 0);
            }
        }
        __syncthreads();
    }
    float* Po = P + (size_t)bz * BB * DD;
    #pragma unroll
    for (int mi = 0; mi < 2; ++mi)
        #pragma unroll
        for (int nb = 0; nb < 5; ++nb)
            #pragma unroll
            for (int rr = 0; rr < 4; ++rr) {
                int gr = bm * 128 + wv * 32 + mi * 16 + kb * 4 + rr;
                int gc = bn * 80 + nb * 16 + m16;
                Po[(size_t)gr * DD + gc] = acc[mi][nb][rr];
            }
}

// ------ reduce split-K partials + bias, emit bn2 per-column partials -------
__global__ __launch_bounds__(256) void reduce_bn2(const float* __restrict__ P,
                                                  const float* __restrict__ bias2,
                                                  float* __restrict__ out,
                                                  float* __restrict__ part) {
    int blk = blockIdx.x, tid = threadIdx.x;   // 128 blocks x 64 rows
    int r0 = blk * 64;
    const size_t S = (size_t)BB * DD;
    bool hasb = tid < DD - 256;
    float bia = bias2[tid];
    float bib = hasb ? bias2[256 + tid] : 0.f;
    float s1a = 0.f, s2a = 0.f, s1b = 0.f, s2b = 0.f;
    for (int r = 0; r < 64; ++r) {
        size_t base = (size_t)(r0 + r) * DD;
        float v = P[base + tid] + P[S + base + tid] + P[2 * S + base + tid] + P[3 * S + base + tid] + bia;
        out[base + tid] = v;
        s1a += v; s2a = fmaf(v, v, s2a);
        if (hasb) {
            size_t b2i = base + 256 + tid;
            float u = P[b2i] + P[S + b2i] + P[2 * S + b2i] + P[3 * S + b2i] + bib;
            out[b2i] = u;
            s1b += u; s2b = fmaf(u, u, s2b);
        }
    }
    float* p = part + (size_t)blk * (DD * 2);
    p[tid * 2] = s1a; p[tid * 2 + 1] = s2a;
    if (hasb) { p[(256 + tid) * 2] = s1b; p[(256 + tid) * 2 + 1] = s2b; }
}

__global__ __launch_bounds__(128) void bn2_fin(const float* __restrict__ part,
                                               const float* __restrict__ g2,
                                               const float* __restrict__ b2,
                                               float* __restrict__ sc,
                                               float* __restrict__ sh) {
    __shared__ float red[4];
    int col = blockIdx.x, tid = threadIdx.x;
    float s1 = part[(size_t)tid * (DD * 2) + col * 2];
    float s2 = part[(size_t)tid * (DD * 2) + col * 2 + 1];
    #pragma unroll
    for (int m = 1; m < 64; m <<= 1) { s1 += __shfl_xor(s1, m); s2 += __shfl_xor(s2, m); }
    int wv = tid >> 6;
    if ((tid & 63) == 0) { red[wv] = s1; red[2 + wv] = s2; }
    __syncthreads();
    if (tid == 0) {
        double t1 = (double)red[0] + red[1];
        double t2 = (double)red[2] + red[3];
        double mean = t1 / (double)BB;
        double var = t2 / (double)BB - mean * mean;
        float s = (float)((double)g2[col] / sqrt(var + EPSF));
        sc[col] = s;
        sh[col] = (float)((double)b2[col] - mean * s);
    }
}

__global__ __launch_bounds__(256) void final_k(float* __restrict__ out,
                                               const float* __restrict__ sc,
                                               const float* __restrict__ sh) {
    __shared__ float lsc[DD], lsh[DD];
    int tid = threadIdx.x;
    for (int c = tid; c < DD; c += 256) { lsc[c] = sc[c]; lsh[c] = sh[c]; }
    __syncthreads();
    size_t base = (size_t)blockIdx.x * 4 * DD;
    for (int r = 0; r < 4; ++r)
        for (int c = tid; c < DD; c += 256) {
            size_t i = base + (size_t)r * DD + c;
            float v = fmaf(out[i], lsc[c], lsh[c]);
            out[i] = v > 0.f ? v : 0.f;
        }
}

// ---------------------------------------------------------------------------
extern "C" void kernel_launch(void* const* d_in, const int* in_sizes, int n_in,
                              void* d_out, int out_size, void* d_ws, size_t ws_size,
                              hipStream_t stream) {
    const int* ht      = (const int*)d_in[0];
    const float* UE    = (const float*)d_in[1];
    const float* W_E   = (const float*)d_in[2];
    const float* fc1_w = (const float*)d_in[3];
    const float* fc1_b = (const float*)d_in[4];
    const float* fc_w  = (const float*)d_in[5];
    const float* fc_b  = (const float*)d_in[6];
    const float* bn0_g = (const float*)d_in[7];
    const float* bn0_b = (const float*)d_in[8];
    const float* bn1_g = (const float*)d_in[9];
    const float* bn1_b = (const float*)d_in[10];
    const float* bn2_g = (const float*)d_in[11];
    const float* bn2_b = (const float*)d_in[12];
    float* out = (float*)d_out;

    char* w = (char*)d_ws;
    unsigned short* convb = (unsigned short*)w; w += (size_t)BB * FCLEN * 2;      // 205.5 MB
    unsigned short* Bprep = (unsigned short*)w; w += (size_t)DD * FCLEN * 2;      // 10 MB
    float* chpartT = (float*)w; w += (size_t)2 * OCC * BB * 4;                    // 2.1 MB
    float* bn0p = (float*)w;  w += 256 * 2 * 4;
    float* ab0 = (float*)w;   w += 64;
    float* alphabeta = (float*)w; w += 64 * 4;
    float* bias2 = (float*)w; w += DD * 4;
    float* bn2p = (float*)w;  w += (size_t)128 * DD * 2 * 4;
    float* bn2sc = (float*)w; w += DD * 4;
    float* bn2sh = (float*)w; w += DD * 4;
    // split-K partial region (52.4 MB), aliased over head/kbuf/Mbuf (dead by
    // the time fc_gemm_sk runs):
    float* P = (float*)w;     w += (size_t)KSPL * BB * DD * 4;
    float* head = P;                      // 13.1 MB, consumed by conv_k/bn0
    float* kbuf = head + (size_t)BB * DD; // 9.4 MB, consumed by conv_k
    float* Mbuf = kbuf + (size_t)BB * RR; // 0.46 MB, consumed by gemm_s1<96>
    (void)ws_size; (void)in_sizes; (void)n_in; (void)out_size;

    prep_M<<<dim3(RR / 16, DD / 16), dim3(16, 16), 0, stream>>>(W_E, fc1_w, Mbuf);
    gemm_s1<80><<<dim3(BB / 64, DD / 80), 256, 0, stream>>>(UE, ht, W_E, nullptr, head, DD);
    gemm_s1<96><<<dim3(BB / 64, RR / 96), 256, 0, stream>>>(UE, ht + BB, Mbuf, fc1_b, kbuf, RR);
    bn0_part<<<256, 256, 0, stream>>>(head, bn0p);
    bn0_fin<<<1, 256, 0, stream>>>(bn0p, bn0_g, bn0_b, ab0);
    conv_k<<<BB, 256, 0, stream>>>(head, kbuf, ab0, convb, chpartT);
    bn1_fin<<<OCC, 256, 0, stream>>>(chpartT, bn1_g, bn1_b, alphabeta);
    prep_fcw<<<DD, 256, 0, stream>>>(fc_w, fc_b, alphabeta, Bprep, bias2);
    fc_gemm_sk<<<dim3(BB / 128, DD / 80, KSPL), 256, 0, stream>>>(convb, Bprep, P);
    reduce_bn2<<<128, 256, 0, stream>>>(P, bias2, out, bn2p);
    bn2_fin<<<DD, 128, 0, stream>>>(bn2p, bn2_g, bn2_b, bn2sc, bn2sh);
    final_k<<<2048, 256, 0, stream>>>(out, bn2sc, bn2sh);
}